// Round 3
// baseline (2220.147 us; speedup 1.0000x reference)
//
#include <hip/hip_runtime.h>
#include <hip/hip_bf16.h>

// LSTM: B=64, T=2048, D=128, H=128, gates 4H=512.
// Kernel 1: xg[b][t][g] = sum_d x[b,t,d]*Wx[d,g] + bias[g]   (parallel GEMM)
// Kernel 2: per-batch sequential recurrence, 1 block/batch, 1024 threads.
//   Thread (g, kh): column g of Wh, K-half kh = 64 weights in 16 float4s.
//   R1 (VGPR=80/128 floats) and R2 (VGPR=48/64 floats) proved LLVM
//   rematerializes the invariant Wh loads inside the loop instead of keeping
//   them live. Fix: pipe each loaded value through asm volatile "+v" — an
//   inline-asm result is not rematerializable, forcing register residency.

#define B_ 64
#define T_ 2048
#define D_ 128
#define H_ 128
#define G_ 512  // 4*H

__device__ __forceinline__ float fast_exp2(float x) { return __builtin_amdgcn_exp2f(x); }
__device__ __forceinline__ float fast_rcp(float x)  { return __builtin_amdgcn_rcpf(x); }
__device__ __forceinline__ float sigmoid_(float x) {
    return fast_rcp(1.0f + fast_exp2(x * -1.44269504088896341f));
}
__device__ __forceinline__ float tanh_(float x) {
    // tanh(x) = 1 - 2/(1+2^(x*2*log2e)); saturates correctly at +-inf.
    return 1.0f - 2.0f * fast_rcp(1.0f + fast_exp2(x * 2.88539008177792682f));
}

// ---------------- Kernel 1: input projection GEMM ----------------
__global__ void __launch_bounds__(256, 2)
xg_gemm_kernel(const float* __restrict__ x, const float* __restrict__ Wx,
               const float* __restrict__ bias, float* __restrict__ xg,
               int t0, int C) {
    __shared__ float xs[64 * 128];  // 32 KB: 64 rows of x
    const int tid = threadIdx.x;
    const int block_row = blockIdx.x * 64;   // row index in [0, B*C)
    const int b  = block_row / C;
    const int tl = block_row - b * C;

    const float* xrow = x + ((size_t)b * T_ + (size_t)(t0 + tl)) * D_;
    const float4* xv = (const float4*)xrow;
    float4* xsv = (float4*)xs;
#pragma unroll
    for (int i = 0; i < 8; ++i) xsv[tid + 256 * i] = xv[tid + 256 * i];
    __syncthreads();

    const int rg = tid >> 5;   // 0..7
    const int cg = tid & 31;   // 0..31

    float acc[8][16];
#pragma unroll
    for (int j2 = 0; j2 < 4; ++j2) {
        float4 bb = *(const float4*)&bias[j2 * 128 + cg * 4];
#pragma unroll
        for (int r = 0; r < 8; ++r) {
            acc[r][j2 * 4 + 0] = bb.x; acc[r][j2 * 4 + 1] = bb.y;
            acc[r][j2 * 4 + 2] = bb.z; acc[r][j2 * 4 + 3] = bb.w;
        }
    }

#pragma unroll 2
    for (int k = 0; k < 128; ++k) {
        float4 w0 = *(const float4*)&Wx[(size_t)k * G_ + 0 * 128 + cg * 4];
        float4 w1 = *(const float4*)&Wx[(size_t)k * G_ + 1 * 128 + cg * 4];
        float4 w2 = *(const float4*)&Wx[(size_t)k * G_ + 2 * 128 + cg * 4];
        float4 w3 = *(const float4*)&Wx[(size_t)k * G_ + 3 * 128 + cg * 4];
#pragma unroll
        for (int r = 0; r < 8; ++r) {
            float xval = xs[(rg * 8 + r) * 128 + k];
            acc[r][0]  = fmaf(xval, w0.x, acc[r][0]);
            acc[r][1]  = fmaf(xval, w0.y, acc[r][1]);
            acc[r][2]  = fmaf(xval, w0.z, acc[r][2]);
            acc[r][3]  = fmaf(xval, w0.w, acc[r][3]);
            acc[r][4]  = fmaf(xval, w1.x, acc[r][4]);
            acc[r][5]  = fmaf(xval, w1.y, acc[r][5]);
            acc[r][6]  = fmaf(xval, w1.z, acc[r][6]);
            acc[r][7]  = fmaf(xval, w1.w, acc[r][7]);
            acc[r][8]  = fmaf(xval, w2.x, acc[r][8]);
            acc[r][9]  = fmaf(xval, w2.y, acc[r][9]);
            acc[r][10] = fmaf(xval, w2.z, acc[r][10]);
            acc[r][11] = fmaf(xval, w2.w, acc[r][11]);
            acc[r][12] = fmaf(xval, w3.x, acc[r][12]);
            acc[r][13] = fmaf(xval, w3.y, acc[r][13]);
            acc[r][14] = fmaf(xval, w3.z, acc[r][14]);
            acc[r][15] = fmaf(xval, w3.w, acc[r][15]);
        }
    }

#pragma unroll
    for (int r = 0; r < 8; ++r) {
#pragma unroll
        for (int j2 = 0; j2 < 4; ++j2) {
            float4 v;
            v.x = acc[r][j2 * 4 + 0]; v.y = acc[r][j2 * 4 + 1];
            v.z = acc[r][j2 * 4 + 2]; v.w = acc[r][j2 * 4 + 3];
            *(float4*)&xg[((size_t)block_row + rg * 8 + r) * G_ + j2 * 128 + cg * 4] = v;
        }
    }
}

// ---------------- Kernel 2: sequential recurrence ----------------
// 64 blocks x 1024 threads. tid = kh*512 + g.

#define LOADW(i) \
    float4 wh##i; \
    wh##i.x = Wh[(size_t)(k0 + i * 4 + 0) * G_ + g]; \
    wh##i.y = Wh[(size_t)(k0 + i * 4 + 1) * G_ + g]; \
    wh##i.z = Wh[(size_t)(k0 + i * 4 + 2) * G_ + g]; \
    wh##i.w = Wh[(size_t)(k0 + i * 4 + 3) * G_ + g];

// Inline-asm identity: result is not rematerializable -> must stay in VGPRs.
#define PINW(i) \
    asm volatile("" : "+v"(wh##i.x), "+v"(wh##i.y), "+v"(wh##i.z), "+v"(wh##i.w));

#define FMA4(i) { \
    float4 h4 = *(const float4*)&h_lds[k0 + i * 4]; \
    acc = fmaf(h4.x, wh##i.x, acc); \
    acc = fmaf(h4.y, wh##i.y, acc); \
    acc = fmaf(h4.z, wh##i.z, acc); \
    acc = fmaf(h4.w, wh##i.w, acc); }

__global__ void __launch_bounds__(1024, 4)
lstm_rnn_kernel(const float* __restrict__ xg, const float* __restrict__ Wh,
                float* __restrict__ hs, float* __restrict__ cs,
                float* __restrict__ hstate, float* __restrict__ cstate,
                int t0, int C) {
    const int b   = blockIdx.x;
    const int tid = threadIdx.x;
    const int g   = tid & 511;   // gate column
    const int kh  = tid >> 9;    // K half (wave-uniform)
    const int k0  = kh * 64;

    __shared__ __align__(16) float h_lds[H_];
    __shared__ __align__(16) float partial[1024];

    LOADW(0)  LOADW(1)  LOADW(2)  LOADW(3)
    LOADW(4)  LOADW(5)  LOADW(6)  LOADW(7)
    LOADW(8)  LOADW(9)  LOADW(10) LOADW(11)
    LOADW(12) LOADW(13) LOADW(14) LOADW(15)
    PINW(0)  PINW(1)  PINW(2)  PINW(3)
    PINW(4)  PINW(5)  PINW(6)  PINW(7)
    PINW(8)  PINW(9)  PINW(10) PINW(11)
    PINW(12) PINW(13) PINW(14) PINW(15)

    float c = 0.0f;
    if (tid < H_) {
        float hv = 0.0f;
        if (t0 > 0) { hv = hstate[b * H_ + tid]; c = cstate[b * H_ + tid]; }
        h_lds[tid] = hv;
    }
    __syncthreads();

    const float* xgb = xg + (size_t)b * C * G_;
    float xg_next = (kh == 0) ? xgb[g] : 0.0f;

    for (int t = 0; t < C; ++t) {
        float acc = xg_next;
        int tn = (t + 1 < C) ? (t + 1) : t;
        if (kh == 0) xg_next = xgb[(size_t)tn * G_ + g];  // wave-uniform prefetch
        else         xg_next = 0.0f;

        FMA4(0)  FMA4(1)  FMA4(2)  FMA4(3)
        FMA4(4)  FMA4(5)  FMA4(6)  FMA4(7)
        FMA4(8)  FMA4(9)  FMA4(10) FMA4(11)
        FMA4(12) FMA4(13) FMA4(14) FMA4(15)

        partial[tid] = acc;
        __syncthreads();

        if (tid < H_) {
            float pi = partial[tid]       + partial[tid + 512];
            float pf = partial[tid + 128] + partial[tid + 640];
            float pg = partial[tid + 256] + partial[tid + 768];
            float po = partial[tid + 384] + partial[tid + 896];
            float iv = sigmoid_(pi);
            float fv = sigmoid_(pf);
            float gv = tanh_(pg);
            float ov = sigmoid_(po);
            c = fmaf(fv, c, iv * gv);
            float hn = ov * tanh_(c);
            h_lds[tid] = hn;
            size_t off = ((size_t)b * T_ + (size_t)(t0 + t)) * H_ + tid;
            hs[off] = hn;
            cs[off] = c;
        }
        __syncthreads();
    }

    if (tid < H_) {
        hstate[b * H_ + tid] = h_lds[tid];
        cstate[b * H_ + tid] = c;
    }
}

extern "C" void kernel_launch(void* const* d_in, const int* in_sizes, int n_in,
                              void* d_out, int out_size, void* d_ws, size_t ws_size,
                              hipStream_t stream) {
    const float* x    = (const float*)d_in[0];  // [64,2048,128]
    const float* Wx   = (const float*)d_in[1];  // [128,512]
    const float* Wh   = (const float*)d_in[2];  // [128,512]
    const float* bias = (const float*)d_in[3];  // [512]

    float* hs = (float*)d_out;                         // [64,2048,128]
    float* cs = hs + (size_t)B_ * T_ * H_;             // [64,2048,128]

    float* hstate = (float*)d_ws;                      // [64,128]
    float* cstate = hstate + B_ * H_;                  // [64,128]
    float* xg     = cstate + B_ * H_;                  // chunk scratch [B][C][512]

    const size_t state_floats = (size_t)2 * B_ * H_;
    size_t avail_bytes = (ws_size > state_floats * 4) ? (ws_size - state_floats * 4) : 0;
    const size_t bytes_per_t = (size_t)B_ * G_ * sizeof(float);

    int C = (int)(avail_bytes / bytes_per_t);
    if (C > T_) C = T_;
    C &= ~63;
    if (C < 64) C = 64;

    for (int t0 = 0; t0 < T_; t0 += C) {
        int Ci = (T_ - t0 < C) ? (T_ - t0) : C;
        dim3 ggrid((B_ * Ci) / 64);
        xg_gemm_kernel<<<ggrid, 256, 0, stream>>>(x, Wx, bias, xg, t0, Ci);
        lstm_rnn_kernel<<<B_, 1024, 0, stream>>>(xg, Wh, hs, cs, hstate, cstate, t0, Ci);
    }
}

// Round 4
// 2196.083 us; speedup vs baseline: 1.0110x; 1.0110x over previous
//
#include <hip/hip_runtime.h>
#include <hip/hip_bf16.h>

// LSTM: B=64, T=2048, D=128, H=128, gates 4H=512.
// Kernel 1: xg[b][t][g] = sum_d x[b,t,d]*Wx[d,g] + bias[g]   (parallel GEMM)
// Kernel 2: per-batch sequential recurrence, 1 block/batch, 1024 threads.
//   R1-R3 showed the occupancy-driven RA squeezed VGPRs to 48 (2 blocks/CU
//   target) and demoted the per-thread Wh slice to reloads. Grid is 64 blocks
//   on 256 CUs -> extra occupancy is worthless. amdgpu_waves_per_eu(4,4)
//   pins the occupancy target so the RA can use the full 128-VGPR budget.

#define B_ 64
#define T_ 2048
#define D_ 128
#define H_ 128
#define G_ 512  // 4*H

__device__ __forceinline__ float fast_exp2(float x) { return __builtin_amdgcn_exp2f(x); }
__device__ __forceinline__ float fast_rcp(float x)  { return __builtin_amdgcn_rcpf(x); }
__device__ __forceinline__ float sigmoid_(float x) {
    return fast_rcp(1.0f + fast_exp2(x * -1.44269504088896341f));
}
__device__ __forceinline__ float tanh_(float x) {
    // tanh(x) = 1 - 2/(1+2^(x*2*log2e)); saturates correctly at +-inf.
    return 1.0f - 2.0f * fast_rcp(1.0f + fast_exp2(x * 2.88539008177792682f));
}

// ---------------- Kernel 1: input projection GEMM ----------------
__global__ void __launch_bounds__(256, 2)
xg_gemm_kernel(const float* __restrict__ x, const float* __restrict__ Wx,
               const float* __restrict__ bias, float* __restrict__ xg,
               int t0, int C) {
    __shared__ float xs[64 * 128];  // 32 KB: 64 rows of x
    const int tid = threadIdx.x;
    const int block_row = blockIdx.x * 64;   // row index in [0, B*C)
    const int b  = block_row / C;
    const int tl = block_row - b * C;

    const float* xrow = x + ((size_t)b * T_ + (size_t)(t0 + tl)) * D_;
    const float4* xv = (const float4*)xrow;
    float4* xsv = (float4*)xs;
#pragma unroll
    for (int i = 0; i < 8; ++i) xsv[tid + 256 * i] = xv[tid + 256 * i];
    __syncthreads();

    const int rg = tid >> 5;   // 0..7
    const int cg = tid & 31;   // 0..31

    float acc[8][16];
#pragma unroll
    for (int j2 = 0; j2 < 4; ++j2) {
        float4 bb = *(const float4*)&bias[j2 * 128 + cg * 4];
#pragma unroll
        for (int r = 0; r < 8; ++r) {
            acc[r][j2 * 4 + 0] = bb.x; acc[r][j2 * 4 + 1] = bb.y;
            acc[r][j2 * 4 + 2] = bb.z; acc[r][j2 * 4 + 3] = bb.w;
        }
    }

#pragma unroll 2
    for (int k = 0; k < 128; ++k) {
        float4 w0 = *(const float4*)&Wx[(size_t)k * G_ + 0 * 128 + cg * 4];
        float4 w1 = *(const float4*)&Wx[(size_t)k * G_ + 1 * 128 + cg * 4];
        float4 w2 = *(const float4*)&Wx[(size_t)k * G_ + 2 * 128 + cg * 4];
        float4 w3 = *(const float4*)&Wx[(size_t)k * G_ + 3 * 128 + cg * 4];
#pragma unroll
        for (int r = 0; r < 8; ++r) {
            float xval = xs[(rg * 8 + r) * 128 + k];
            acc[r][0]  = fmaf(xval, w0.x, acc[r][0]);
            acc[r][1]  = fmaf(xval, w0.y, acc[r][1]);
            acc[r][2]  = fmaf(xval, w0.z, acc[r][2]);
            acc[r][3]  = fmaf(xval, w0.w, acc[r][3]);
            acc[r][4]  = fmaf(xval, w1.x, acc[r][4]);
            acc[r][5]  = fmaf(xval, w1.y, acc[r][5]);
            acc[r][6]  = fmaf(xval, w1.z, acc[r][6]);
            acc[r][7]  = fmaf(xval, w1.w, acc[r][7]);
            acc[r][8]  = fmaf(xval, w2.x, acc[r][8]);
            acc[r][9]  = fmaf(xval, w2.y, acc[r][9]);
            acc[r][10] = fmaf(xval, w2.z, acc[r][10]);
            acc[r][11] = fmaf(xval, w2.w, acc[r][11]);
            acc[r][12] = fmaf(xval, w3.x, acc[r][12]);
            acc[r][13] = fmaf(xval, w3.y, acc[r][13]);
            acc[r][14] = fmaf(xval, w3.z, acc[r][14]);
            acc[r][15] = fmaf(xval, w3.w, acc[r][15]);
        }
    }

#pragma unroll
    for (int r = 0; r < 8; ++r) {
#pragma unroll
        for (int j2 = 0; j2 < 4; ++j2) {
            float4 v;
            v.x = acc[r][j2 * 4 + 0]; v.y = acc[r][j2 * 4 + 1];
            v.z = acc[r][j2 * 4 + 2]; v.w = acc[r][j2 * 4 + 3];
            *(float4*)&xg[((size_t)block_row + rg * 8 + r) * G_ + j2 * 128 + cg * 4] = v;
        }
    }
}

// ---------------- Kernel 2: sequential recurrence ----------------
// 64 blocks x 1024 threads. tid = kh*512 + g.

#define LOADW(i) \
    float4 wh##i; \
    wh##i.x = Wh[(size_t)(k0 + i * 4 + 0) * G_ + g]; \
    wh##i.y = Wh[(size_t)(k0 + i * 4 + 1) * G_ + g]; \
    wh##i.z = Wh[(size_t)(k0 + i * 4 + 2) * G_ + g]; \
    wh##i.w = Wh[(size_t)(k0 + i * 4 + 3) * G_ + g];

// Inline-asm identity: result is not rematerializable.
#define PINW(i) \
    asm volatile("" : "+v"(wh##i.x), "+v"(wh##i.y), "+v"(wh##i.z), "+v"(wh##i.w));

#define FMA4(i) { \
    float4 h4 = *(const float4*)&h_lds[k0 + i * 4]; \
    acc = fmaf(h4.x, wh##i.x, acc); \
    acc = fmaf(h4.y, wh##i.y, acc); \
    acc = fmaf(h4.z, wh##i.z, acc); \
    acc = fmaf(h4.w, wh##i.w, acc); }

__global__ void __launch_bounds__(1024)
__attribute__((amdgpu_waves_per_eu(4, 4)))
lstm_rnn_kernel(const float* __restrict__ xg, const float* __restrict__ Wh,
                float* __restrict__ hs, float* __restrict__ cs,
                float* __restrict__ hstate, float* __restrict__ cstate,
                int t0, int C) {
    const int b   = blockIdx.x;
    const int tid = threadIdx.x;
    const int g   = tid & 511;   // gate column
    const int kh  = tid >> 9;    // K half (wave-uniform)
    const int k0  = kh * 64;

    __shared__ __align__(16) float h_lds[H_];
    __shared__ __align__(16) float partial[1024];

    LOADW(0)  LOADW(1)  LOADW(2)  LOADW(3)
    LOADW(4)  LOADW(5)  LOADW(6)  LOADW(7)
    LOADW(8)  LOADW(9)  LOADW(10) LOADW(11)
    LOADW(12) LOADW(13) LOADW(14) LOADW(15)
    PINW(0)  PINW(1)  PINW(2)  PINW(3)
    PINW(4)  PINW(5)  PINW(6)  PINW(7)
    PINW(8)  PINW(9)  PINW(10) PINW(11)
    PINW(12) PINW(13) PINW(14) PINW(15)

    float c = 0.0f;
    if (tid < H_) {
        float hv = 0.0f;
        if (t0 > 0) { hv = hstate[b * H_ + tid]; c = cstate[b * H_ + tid]; }
        h_lds[tid] = hv;
    }
    __syncthreads();

    const float* xgb = xg + (size_t)b * C * G_;
    float xg_next = (kh == 0) ? xgb[g] : 0.0f;

    for (int t = 0; t < C; ++t) {
        float acc = xg_next;
        int tn = (t + 1 < C) ? (t + 1) : t;
        if (kh == 0) xg_next = xgb[(size_t)tn * G_ + g];  // wave-uniform prefetch
        else         xg_next = 0.0f;

        FMA4(0)  FMA4(1)  FMA4(2)  FMA4(3)
        FMA4(4)  FMA4(5)  FMA4(6)  FMA4(7)
        FMA4(8)  FMA4(9)  FMA4(10) FMA4(11)
        FMA4(12) FMA4(13) FMA4(14) FMA4(15)

        partial[tid] = acc;
        __syncthreads();

        if (tid < H_) {
            float pi = partial[tid]       + partial[tid + 512];
            float pf = partial[tid + 128] + partial[tid + 640];
            float pg = partial[tid + 256] + partial[tid + 768];
            float po = partial[tid + 384] + partial[tid + 896];
            float iv = sigmoid_(pi);
            float fv = sigmoid_(pf);
            float gv = tanh_(pg);
            float ov = sigmoid_(po);
            c = fmaf(fv, c, iv * gv);
            float hn = ov * tanh_(c);
            h_lds[tid] = hn;
            size_t off = ((size_t)b * T_ + (size_t)(t0 + t)) * H_ + tid;
            hs[off] = hn;
            cs[off] = c;
        }
        __syncthreads();
    }

    if (tid < H_) {
        hstate[b * H_ + tid] = h_lds[tid];
        cstate[b * H_ + tid] = c;
    }
}

extern "C" void kernel_launch(void* const* d_in, const int* in_sizes, int n_in,
                              void* d_out, int out_size, void* d_ws, size_t ws_size,
                              hipStream_t stream) {
    const float* x    = (const float*)d_in[0];  // [64,2048,128]
    const float* Wx   = (const float*)d_in[1];  // [128,512]
    const float* Wh   = (const float*)d_in[2];  // [128,512]
    const float* bias = (const float*)d_in[3];  // [512]

    float* hs = (float*)d_out;                         // [64,2048,128]
    float* cs = hs + (size_t)B_ * T_ * H_;             // [64,2048,128]

    float* hstate = (float*)d_ws;                      // [64,128]
    float* cstate = hstate + B_ * H_;                  // [64,128]
    float* xg     = cstate + B_ * H_;                  // chunk scratch [B][C][512]

    const size_t state_floats = (size_t)2 * B_ * H_;
    size_t avail_bytes = (ws_size > state_floats * 4) ? (ws_size - state_floats * 4) : 0;
    const size_t bytes_per_t = (size_t)B_ * G_ * sizeof(float);

    int C = (int)(avail_bytes / bytes_per_t);
    if (C > T_) C = T_;
    C &= ~63;
    if (C < 64) C = 64;

    for (int t0 = 0; t0 < T_; t0 += C) {
        int Ci = (T_ - t0 < C) ? (T_ - t0) : C;
        dim3 ggrid((B_ * Ci) / 64);
        xg_gemm_kernel<<<ggrid, 256, 0, stream>>>(x, Wx, bias, xg, t0, Ci);
        lstm_rnn_kernel<<<B_, 1024, 0, stream>>>(xg, Wh, hs, cs, hstate, cstate, t0, Ci);
    }
}

// Round 5
// 1928.350 us; speedup vs baseline: 1.1513x; 1.1388x over previous
//
#include <hip/hip_runtime.h>
#include <hip/hip_bf16.h>

// LSTM: B=64, T=2048, D=128, H=128, gates 4H=512.
// Kernel 1: xg[b][t][g] = sum_d x[b,t,d]*Wx[d,g] + bias[g]   (parallel GEMM)
// Kernel 2: per-batch recurrence, 64 blocks x 512 threads (1 block/CU).
//   R1-R4: allocator spilled/remat'd the per-thread Wh slice at every
//   occupancy target tried with 1024-thread blocks (VGPR stuck at 48-52).
//   Now: 512 threads -> 2 waves/EU -> 256-VGPR budget via waves_per_eu(2,2);
//   thread g owns the whole column (128 weights = 32 float4). Non-volatile
//   asm "+v" identity pins INSIDE the loop create loop-carried deps whose
//   def is inline asm => not rematerializable => must stay in VGPRs.

#define B_ 64
#define T_ 2048
#define D_ 128
#define H_ 128
#define G_ 512  // 4*H

__device__ __forceinline__ float fast_exp2(float x) { return __builtin_amdgcn_exp2f(x); }
__device__ __forceinline__ float fast_rcp(float x)  { return __builtin_amdgcn_rcpf(x); }
__device__ __forceinline__ float sigmoid_(float x) {
    return fast_rcp(1.0f + fast_exp2(x * -1.44269504088896341f));
}
__device__ __forceinline__ float tanh_(float x) {
    // tanh(x) = 1 - 2/(1+2^(x*2*log2e)); saturates correctly at +-inf.
    return 1.0f - 2.0f * fast_rcp(1.0f + fast_exp2(x * 2.88539008177792682f));
}

// ---------------- Kernel 1: input projection GEMM ----------------
__global__ void __launch_bounds__(256, 2)
xg_gemm_kernel(const float* __restrict__ x, const float* __restrict__ Wx,
               const float* __restrict__ bias, float* __restrict__ xg,
               int t0, int C) {
    __shared__ float xs[64 * 128];  // 32 KB: 64 rows of x
    const int tid = threadIdx.x;
    const int block_row = blockIdx.x * 64;   // row index in [0, B*C)
    const int b  = block_row / C;
    const int tl = block_row - b * C;

    const float* xrow = x + ((size_t)b * T_ + (size_t)(t0 + tl)) * D_;
    const float4* xv = (const float4*)xrow;
    float4* xsv = (float4*)xs;
#pragma unroll
    for (int i = 0; i < 8; ++i) xsv[tid + 256 * i] = xv[tid + 256 * i];
    __syncthreads();

    const int rg = tid >> 5;   // 0..7
    const int cg = tid & 31;   // 0..31

    float acc[8][16];
#pragma unroll
    for (int j2 = 0; j2 < 4; ++j2) {
        float4 bb = *(const float4*)&bias[j2 * 128 + cg * 4];
#pragma unroll
        for (int r = 0; r < 8; ++r) {
            acc[r][j2 * 4 + 0] = bb.x; acc[r][j2 * 4 + 1] = bb.y;
            acc[r][j2 * 4 + 2] = bb.z; acc[r][j2 * 4 + 3] = bb.w;
        }
    }

#pragma unroll 2
    for (int k = 0; k < 128; ++k) {
        float4 w0 = *(const float4*)&Wx[(size_t)k * G_ + 0 * 128 + cg * 4];
        float4 w1 = *(const float4*)&Wx[(size_t)k * G_ + 1 * 128 + cg * 4];
        float4 w2 = *(const float4*)&Wx[(size_t)k * G_ + 2 * 128 + cg * 4];
        float4 w3 = *(const float4*)&Wx[(size_t)k * G_ + 3 * 128 + cg * 4];
#pragma unroll
        for (int r = 0; r < 8; ++r) {
            float xval = xs[(rg * 8 + r) * 128 + k];
            acc[r][0]  = fmaf(xval, w0.x, acc[r][0]);
            acc[r][1]  = fmaf(xval, w0.y, acc[r][1]);
            acc[r][2]  = fmaf(xval, w0.z, acc[r][2]);
            acc[r][3]  = fmaf(xval, w0.w, acc[r][3]);
            acc[r][4]  = fmaf(xval, w1.x, acc[r][4]);
            acc[r][5]  = fmaf(xval, w1.y, acc[r][5]);
            acc[r][6]  = fmaf(xval, w1.z, acc[r][6]);
            acc[r][7]  = fmaf(xval, w1.w, acc[r][7]);
            acc[r][8]  = fmaf(xval, w2.x, acc[r][8]);
            acc[r][9]  = fmaf(xval, w2.y, acc[r][9]);
            acc[r][10] = fmaf(xval, w2.z, acc[r][10]);
            acc[r][11] = fmaf(xval, w2.w, acc[r][11]);
            acc[r][12] = fmaf(xval, w3.x, acc[r][12]);
            acc[r][13] = fmaf(xval, w3.y, acc[r][13]);
            acc[r][14] = fmaf(xval, w3.z, acc[r][14]);
            acc[r][15] = fmaf(xval, w3.w, acc[r][15]);
        }
    }

#pragma unroll
    for (int r = 0; r < 8; ++r) {
#pragma unroll
        for (int j2 = 0; j2 < 4; ++j2) {
            float4 v;
            v.x = acc[r][j2 * 4 + 0]; v.y = acc[r][j2 * 4 + 1];
            v.z = acc[r][j2 * 4 + 2]; v.w = acc[r][j2 * 4 + 3];
            *(float4*)&xg[((size_t)block_row + rg * 8 + r) * G_ + j2 * 128 + cg * 4] = v;
        }
    }
}

// ---------------- Kernel 2: sequential recurrence ----------------
// 64 blocks x 512 threads. Thread g owns full column g: 128 weights in 32
// named float4s. Non-volatile asm identity pins inside the loop make the
// weight values loop-carried (def = inline asm -> not rematerializable).

#define LOADW(i) \
    float4 wh##i; \
    wh##i.x = Wh[(size_t)(i * 4 + 0) * G_ + g]; \
    wh##i.y = Wh[(size_t)(i * 4 + 1) * G_ + g]; \
    wh##i.z = Wh[(size_t)(i * 4 + 2) * G_ + g]; \
    wh##i.w = Wh[(size_t)(i * 4 + 3) * G_ + g];

#define PINW(i) \
    asm("" : "+v"(wh##i.x), "+v"(wh##i.y), "+v"(wh##i.z), "+v"(wh##i.w));

#define FMA4(i) { \
    float4 h4 = *(const float4*)&h_lds[i * 4]; \
    acc = fmaf(h4.x, wh##i.x, acc); \
    acc = fmaf(h4.y, wh##i.y, acc); \
    acc = fmaf(h4.z, wh##i.z, acc); \
    acc = fmaf(h4.w, wh##i.w, acc); }

__global__ void __launch_bounds__(512)
__attribute__((amdgpu_waves_per_eu(2, 2)))
lstm_rnn_kernel(const float* __restrict__ xg, const float* __restrict__ Wh,
                float* __restrict__ hs, float* __restrict__ cs,
                float* __restrict__ hstate, float* __restrict__ cstate,
                int t0, int C) {
    const int b = blockIdx.x;
    const int g = threadIdx.x;  // 0..511, full column

    __shared__ __align__(16) float h_lds[H_];
    __shared__ __align__(16) float g_lds[G_];

    LOADW(0)  LOADW(1)  LOADW(2)  LOADW(3)
    LOADW(4)  LOADW(5)  LOADW(6)  LOADW(7)
    LOADW(8)  LOADW(9)  LOADW(10) LOADW(11)
    LOADW(12) LOADW(13) LOADW(14) LOADW(15)
    LOADW(16) LOADW(17) LOADW(18) LOADW(19)
    LOADW(20) LOADW(21) LOADW(22) LOADW(23)
    LOADW(24) LOADW(25) LOADW(26) LOADW(27)
    LOADW(28) LOADW(29) LOADW(30) LOADW(31)

    float c = 0.0f;
    if (g < H_) {
        float hv = 0.0f;
        if (t0 > 0) { hv = hstate[b * H_ + g]; c = cstate[b * H_ + g]; }
        h_lds[g] = hv;
    }
    __syncthreads();

    const float* xgb = xg + (size_t)b * C * G_;
    float xg_next = xgb[g];

    for (int t = 0; t < C; ++t) {
        // Loop-carried register pins: forces the 128 weight floats to stay
        // live in VGPRs across the whole loop (cannot be remat'd or sunk).
        PINW(0)  PINW(1)  PINW(2)  PINW(3)
        PINW(4)  PINW(5)  PINW(6)  PINW(7)
        PINW(8)  PINW(9)  PINW(10) PINW(11)
        PINW(12) PINW(13) PINW(14) PINW(15)
        PINW(16) PINW(17) PINW(18) PINW(19)
        PINW(20) PINW(21) PINW(22) PINW(23)
        PINW(24) PINW(25) PINW(26) PINW(27)
        PINW(28) PINW(29) PINW(30) PINW(31)

        float acc = xg_next;
        int tn = (t + 1 < C) ? (t + 1) : t;
        xg_next = xgb[(size_t)tn * G_ + g];  // prefetch next step

        FMA4(0)  FMA4(1)  FMA4(2)  FMA4(3)
        FMA4(4)  FMA4(5)  FMA4(6)  FMA4(7)
        FMA4(8)  FMA4(9)  FMA4(10) FMA4(11)
        FMA4(12) FMA4(13) FMA4(14) FMA4(15)
        FMA4(16) FMA4(17) FMA4(18) FMA4(19)
        FMA4(20) FMA4(21) FMA4(22) FMA4(23)
        FMA4(24) FMA4(25) FMA4(26) FMA4(27)
        FMA4(28) FMA4(29) FMA4(30) FMA4(31)

        g_lds[g] = acc;
        __syncthreads();

        if (g < H_) {
            float pi = g_lds[g];
            float pf = g_lds[g + 128];
            float pg = g_lds[g + 256];
            float po = g_lds[g + 384];
            float iv = sigmoid_(pi);
            float fv = sigmoid_(pf);
            float gv = tanh_(pg);
            float ov = sigmoid_(po);
            c = fmaf(fv, c, iv * gv);
            float hn = ov * tanh_(c);
            h_lds[g] = hn;
            size_t off = ((size_t)b * T_ + (size_t)(t0 + t)) * H_ + g;
            hs[off] = hn;
            cs[off] = c;
        }
        __syncthreads();
    }

    if (g < H_) {
        hstate[b * H_ + g] = h_lds[g];
        cstate[b * H_ + g] = c;
    }
}

extern "C" void kernel_launch(void* const* d_in, const int* in_sizes, int n_in,
                              void* d_out, int out_size, void* d_ws, size_t ws_size,
                              hipStream_t stream) {
    const float* x    = (const float*)d_in[0];  // [64,2048,128]
    const float* Wx   = (const float*)d_in[1];  // [128,512]
    const float* Wh   = (const float*)d_in[2];  // [128,512]
    const float* bias = (const float*)d_in[3];  // [512]

    float* hs = (float*)d_out;                         // [64,2048,128]
    float* cs = hs + (size_t)B_ * T_ * H_;             // [64,2048,128]

    float* hstate = (float*)d_ws;                      // [64,128]
    float* cstate = hstate + B_ * H_;                  // [64,128]
    float* xg     = cstate + B_ * H_;                  // chunk scratch [B][C][512]

    const size_t state_floats = (size_t)2 * B_ * H_;
    size_t avail_bytes = (ws_size > state_floats * 4) ? (ws_size - state_floats * 4) : 0;
    const size_t bytes_per_t = (size_t)B_ * G_ * sizeof(float);

    int C = (int)(avail_bytes / bytes_per_t);
    if (C > T_) C = T_;
    C &= ~63;
    if (C < 64) C = 64;

    for (int t0 = 0; t0 < T_; t0 += C) {
        int Ci = (T_ - t0 < C) ? (T_ - t0) : C;
        dim3 ggrid((B_ * Ci) / 64);
        xg_gemm_kernel<<<ggrid, 256, 0, stream>>>(x, Wx, bias, xg, t0, Ci);
        lstm_rnn_kernel<<<B_, 512, 0, stream>>>(xg, Wh, hs, cs, hstate, cstate, t0, Ci);
    }
}

// Round 6
// 1423.225 us; speedup vs baseline: 1.5599x; 1.3549x over previous
//
#include <hip/hip_runtime.h>
#include <hip/hip_bf16.h>

// LSTM: B=64, T=2048, D=128, H=128, gates 4H=512.
// Kernel 1 (unchanged): xg[b][t][g] = x[b,t,:]@Wx + bias  (exact f32 GEMM)
// Kernel 2 (NEW): recurrence via bf16 MFMA. 64 blocks x 1024 threads.
//   R1-R5: RA never keeps >=64 invariant floats/thread in VGPRs; reloads are
//   L2-BW-bound (~830ns/step floor). MFMA needs only 32 VGPRs/thread of
//   weight fragments (wave w owns N-tiles 2w,2w+1; 8 frags) -> fits any
//   squeeze. M=1 handled by broadcasting h to all 16 A-rows (rows become
//   duplicates; C layout col=lane&15 verified, any reg is the gate value).

#define B_ 64
#define T_ 2048
#define D_ 128
#define H_ 128
#define G_ 512  // 4*H

typedef __bf16 v8bf __attribute__((ext_vector_type(8)));
typedef float f32x4 __attribute__((ext_vector_type(4)));

__device__ __forceinline__ float fast_exp2(float x) { return __builtin_amdgcn_exp2f(x); }
__device__ __forceinline__ float fast_rcp(float x)  { return __builtin_amdgcn_rcpf(x); }
__device__ __forceinline__ float sigmoid_(float x) {
    return fast_rcp(1.0f + fast_exp2(x * -1.44269504088896341f));
}
__device__ __forceinline__ float tanh_(float x) {
    // tanh(x) = 1 - 2/(1+2^(x*2*log2e)); saturates correctly at +-inf.
    return 1.0f - 2.0f * fast_rcp(1.0f + fast_exp2(x * 2.88539008177792682f));
}
__device__ __forceinline__ unsigned short f2bf(float f) {
    union { float f; unsigned u; } v; v.f = f;
    unsigned r = v.u + 0x7FFFu + ((v.u >> 16) & 1u);  // RNE
    return (unsigned short)(r >> 16);
}

// ---------------- Kernel 1: input projection GEMM (f32, exact) ----------------
__global__ void __launch_bounds__(256, 2)
xg_gemm_kernel(const float* __restrict__ x, const float* __restrict__ Wx,
               const float* __restrict__ bias, float* __restrict__ xg,
               int t0, int C) {
    __shared__ float xs[64 * 128];  // 32 KB: 64 rows of x
    const int tid = threadIdx.x;
    const int block_row = blockIdx.x * 64;   // row index in [0, B*C)
    const int b  = block_row / C;
    const int tl = block_row - b * C;

    const float* xrow = x + ((size_t)b * T_ + (size_t)(t0 + tl)) * D_;
    const float4* xv = (const float4*)xrow;
    float4* xsv = (float4*)xs;
#pragma unroll
    for (int i = 0; i < 8; ++i) xsv[tid + 256 * i] = xv[tid + 256 * i];
    __syncthreads();

    const int rg = tid >> 5;   // 0..7
    const int cg = tid & 31;   // 0..31

    float acc[8][16];
#pragma unroll
    for (int j2 = 0; j2 < 4; ++j2) {
        float4 bb = *(const float4*)&bias[j2 * 128 + cg * 4];
#pragma unroll
        for (int r = 0; r < 8; ++r) {
            acc[r][j2 * 4 + 0] = bb.x; acc[r][j2 * 4 + 1] = bb.y;
            acc[r][j2 * 4 + 2] = bb.z; acc[r][j2 * 4 + 3] = bb.w;
        }
    }

#pragma unroll 2
    for (int k = 0; k < 128; ++k) {
        float4 w0 = *(const float4*)&Wx[(size_t)k * G_ + 0 * 128 + cg * 4];
        float4 w1 = *(const float4*)&Wx[(size_t)k * G_ + 1 * 128 + cg * 4];
        float4 w2 = *(const float4*)&Wx[(size_t)k * G_ + 2 * 128 + cg * 4];
        float4 w3 = *(const float4*)&Wx[(size_t)k * G_ + 3 * 128 + cg * 4];
#pragma unroll
        for (int r = 0; r < 8; ++r) {
            float xval = xs[(rg * 8 + r) * 128 + k];
            acc[r][0]  = fmaf(xval, w0.x, acc[r][0]);
            acc[r][1]  = fmaf(xval, w0.y, acc[r][1]);
            acc[r][2]  = fmaf(xval, w0.z, acc[r][2]);
            acc[r][3]  = fmaf(xval, w0.w, acc[r][3]);
            acc[r][4]  = fmaf(xval, w1.x, acc[r][4]);
            acc[r][5]  = fmaf(xval, w1.y, acc[r][5]);
            acc[r][6]  = fmaf(xval, w1.z, acc[r][6]);
            acc[r][7]  = fmaf(xval, w1.w, acc[r][7]);
            acc[r][8]  = fmaf(xval, w2.x, acc[r][8]);
            acc[r][9]  = fmaf(xval, w2.y, acc[r][9]);
            acc[r][10] = fmaf(xval, w2.z, acc[r][10]);
            acc[r][11] = fmaf(xval, w2.w, acc[r][11]);
            acc[r][12] = fmaf(xval, w3.x, acc[r][12]);
            acc[r][13] = fmaf(xval, w3.y, acc[r][13]);
            acc[r][14] = fmaf(xval, w3.z, acc[r][14]);
            acc[r][15] = fmaf(xval, w3.w, acc[r][15]);
        }
    }

#pragma unroll
    for (int r = 0; r < 8; ++r) {
#pragma unroll
        for (int j2 = 0; j2 < 4; ++j2) {
            float4 v;
            v.x = acc[r][j2 * 4 + 0]; v.y = acc[r][j2 * 4 + 1];
            v.z = acc[r][j2 * 4 + 2]; v.w = acc[r][j2 * 4 + 3];
            *(float4*)&xg[((size_t)block_row + rg * 8 + r) * G_ + j2 * 128 + cg * 4] = v;
        }
    }
}

// ---------------- Kernel 2: recurrence via MFMA ----------------
// 64 blocks x 1024 threads (16 waves). Wave w: N-tiles {2w, 2w+1}.
// Per step: acc init = xg (f32, prefetched 2 ahead); 8 mfma_16x16x32_bf16
// accumulate h@Wh; per-wave activation (wave-uniform class); g_act -> LDS;
// barrier; threads 0-127 do c/h update + stores; barrier.

__global__ void __launch_bounds__(1024)
__attribute__((amdgpu_waves_per_eu(4, 4)))
lstm_rnn_mfma(const float* __restrict__ xg, const float* __restrict__ Wh,
              float* __restrict__ hs, float* __restrict__ cs,
              float* __restrict__ hstate, float* __restrict__ cstate,
              int t0, int C) {
    const int b    = blockIdx.x;
    const int tid  = threadIdx.x;
    const int w    = tid >> 6;     // wave 0..15
    const int lane = tid & 63;
    const int q    = lane >> 4;    // k-quarter
    const int cl   = lane & 15;    // col within tile
    const int kb   = q * 8;        // k-base within 32-tile
    const int col0 = (2 * w) * 16 + cl;
    const int col1 = (2 * w + 1) * 16 + cl;

    __shared__ __align__(16) unsigned short h_u16[H_];  // h_t as bf16
    __shared__ __align__(16) float g_act[G_];           // activated gates

    // one-time: Wh B-fragments, bf16. frag(kk, n): lane holds
    // Wh[kk*32 + q*8 + j][col_n], j=0..7. 8 frags = 32 VGPRs.
    v8bf whf[4][2];
#pragma unroll
    for (int kk = 0; kk < 4; ++kk) {
#pragma unroll
        for (int n = 0; n < 2; ++n) {
            const int col = n ? col1 : col0;
            union { unsigned short s[8]; v8bf v; } uw;
#pragma unroll
            for (int j = 0; j < 8; ++j)
                uw.s[j] = f2bf(Wh[(size_t)(kk * 32 + kb + j) * G_ + col]);
            whf[kk][n] = uw.v;
        }
    }

    float c = 0.0f, h_keep = 0.0f;
    if (tid < H_) {
        float hv = 0.0f;
        if (t0 > 0) { hv = hstate[b * H_ + tid]; c = cstate[b * H_ + tid]; }
        h_keep = hv;
        h_u16[tid] = f2bf(hv);
    }
    __syncthreads();

    const bool is_tanh = (w >= 8) && (w < 12);  // tiles 16..23 = g-gate
    const bool writer  = (q == 0);              // lanes 0-15 own the gate copy
    const float* xgb = xg + (size_t)b * C * G_;

    // xg prefetch pipeline, 2 steps deep (hide L3/HBM latency)
    float xA0 = xgb[col0],      xA1 = xgb[col1];        // t
    float xB0 = xgb[G_ + col0], xB1 = xgb[G_ + col1];   // t+1

#define RNN_SUBSTEP(XV0, XV1, TCUR, TPF)                                      \
    {                                                                         \
        f32x4 acc0 = {XV0, XV0, XV0, XV0};                                    \
        f32x4 acc1 = {XV1, XV1, XV1, XV1};                                    \
        int pf = ((TPF) < C) ? (TPF) : (C - 1);                               \
        XV0 = xgb[(size_t)pf * G_ + col0];                                    \
        XV1 = xgb[(size_t)pf * G_ + col1];                                    \
        _Pragma("unroll")                                                     \
        for (int kk = 0; kk < 4; ++kk) {                                      \
            v8bf ha = *(const v8bf*)&h_u16[kk * 32 + kb];                     \
            acc0 = __builtin_amdgcn_mfma_f32_16x16x32_bf16(ha, whf[kk][0], acc0, 0, 0, 0); \
            acc1 = __builtin_amdgcn_mfma_f32_16x16x32_bf16(ha, whf[kk][1], acc1, 0, 0, 0); \
        }                                                                     \
        float a0 = is_tanh ? tanh_(acc0[0]) : sigmoid_(acc0[0]);              \
        float a1 = is_tanh ? tanh_(acc1[0]) : sigmoid_(acc1[0]);              \
        if (writer) { g_act[col0] = a0; g_act[col1] = a1; }                   \
        __syncthreads();                                                      \
        if (tid < H_) {                                                       \
            float iv = g_act[tid],       fv = g_act[128 + tid];               \
            float gv = g_act[256 + tid], ov = g_act[384 + tid];               \
            c = fmaf(fv, c, iv * gv);                                         \
            float hn = ov * tanh_(c);                                         \
            h_keep = hn;                                                      \
            h_u16[tid] = f2bf(hn);                                            \
            size_t off = ((size_t)b * T_ + (size_t)(t0 + (TCUR))) * H_ + tid; \
            hs[off] = hn; cs[off] = c;                                        \
        }                                                                     \
        __syncthreads();                                                      \
    }

    for (int t = 0; t < C; t += 2) {           // C is a multiple of 64
        RNN_SUBSTEP(xA0, xA1, t,     t + 2)
        RNN_SUBSTEP(xB0, xB1, t + 1, t + 3)
    }
#undef RNN_SUBSTEP

    if (tid < H_) {
        hstate[b * H_ + tid] = h_keep;
        cstate[b * H_ + tid] = c;
    }
}

extern "C" void kernel_launch(void* const* d_in, const int* in_sizes, int n_in,
                              void* d_out, int out_size, void* d_ws, size_t ws_size,
                              hipStream_t stream) {
    const float* x    = (const float*)d_in[0];  // [64,2048,128]
    const float* Wx   = (const float*)d_in[1];  // [128,512]
    const float* Wh   = (const float*)d_in[2];  // [128,512]
    const float* bias = (const float*)d_in[3];  // [512]

    float* hs = (float*)d_out;                         // [64,2048,128]
    float* cs = hs + (size_t)B_ * T_ * H_;             // [64,2048,128]

    float* hstate = (float*)d_ws;                      // [64,128]
    float* cstate = hstate + B_ * H_;                  // [64,128]
    float* xg     = cstate + B_ * H_;                  // chunk scratch [B][C][512]

    const size_t state_floats = (size_t)2 * B_ * H_;
    size_t avail_bytes = (ws_size > state_floats * 4) ? (ws_size - state_floats * 4) : 0;
    const size_t bytes_per_t = (size_t)B_ * G_ * sizeof(float);

    int C = (int)(avail_bytes / bytes_per_t);
    if (C > T_) C = T_;
    C &= ~63;
    if (C < 64) C = 64;

    for (int t0 = 0; t0 < T_; t0 += C) {
        int Ci = (T_ - t0 < C) ? (T_ - t0) : C;
        dim3 ggrid((B_ * Ci) / 64);
        xg_gemm_kernel<<<ggrid, 256, 0, stream>>>(x, Wx, bias, xg, t0, Ci);
        lstm_rnn_mfma<<<B_, 1024, 0, stream>>>(xg, Wh, hs, cs, hstate, cstate, t0, Ci);
    }
}

// Round 7
// 1366.895 us; speedup vs baseline: 1.6242x; 1.0412x over previous
//
#include <hip/hip_runtime.h>
#include <hip/hip_bf16.h>

// LSTM: B=64, T=2048, D=128, H=128, gates 4H=512.
// Kernel 1: xg = x@Wx + bias  (exact f32 GEMM, unchanged)
// Kernel 2: recurrence via bf16 MFMA, 64 blocks x 512 threads (8 waves).
//   R6 post-mortem: 2x __syncthreads per step each drained vmcnt(0) (HIP
//   barrier semantics) -> waited on in-flight xg prefetch + hs/cs stores
//   every step (~800 of 1395 cyc/step). This version:
//   - wave w owns ALL FOUR gate tiles (i,f,g,o) for hidden units 16w..16w+15
//     -> c/h update fully in-register, no gate LDS round-trip, no tail waves.
//   - h double-buffered in LDS -> ONE raw s_barrier per step with only
//     lgkmcnt(0) (inline asm); vmcnt never drained in the loop.
//   - 64 VGPRs of Wh fragments @ waves_per_eu(2,2) (256 budget).

#define B_ 64
#define T_ 2048
#define D_ 128
#define H_ 128
#define G_ 512  // 4*H

typedef __bf16 v8bf __attribute__((ext_vector_type(8)));
typedef float f32x4 __attribute__((ext_vector_type(4)));

__device__ __forceinline__ float fast_exp2(float x) { return __builtin_amdgcn_exp2f(x); }
__device__ __forceinline__ float fast_rcp(float x)  { return __builtin_amdgcn_rcpf(x); }
__device__ __forceinline__ float sigmoid_(float x) {
    return fast_rcp(1.0f + fast_exp2(x * -1.44269504088896341f));
}
__device__ __forceinline__ float tanh_(float x) {
    // tanh(x) = 1 - 2/(1+2^(x*2*log2e)); saturates correctly at +-inf.
    return 1.0f - 2.0f * fast_rcp(1.0f + fast_exp2(x * 2.88539008177792682f));
}
__device__ __forceinline__ unsigned short f2bf(float f) {
    union { float f; unsigned u; } v; v.f = f;
    unsigned r = v.u + 0x7FFFu + ((v.u >> 16) & 1u);  // RNE
    return (unsigned short)(r >> 16);
}

// ---------------- Kernel 1: input projection GEMM (f32, exact) ----------------
__global__ void __launch_bounds__(256, 2)
xg_gemm_kernel(const float* __restrict__ x, const float* __restrict__ Wx,
               const float* __restrict__ bias, float* __restrict__ xg,
               int t0, int C) {
    __shared__ float xs[64 * 128];  // 32 KB: 64 rows of x
    const int tid = threadIdx.x;
    const int block_row = blockIdx.x * 64;   // row index in [0, B*C)
    const int b  = block_row / C;
    const int tl = block_row - b * C;

    const float* xrow = x + ((size_t)b * T_ + (size_t)(t0 + tl)) * D_;
    const float4* xv = (const float4*)xrow;
    float4* xsv = (float4*)xs;
#pragma unroll
    for (int i = 0; i < 8; ++i) xsv[tid + 256 * i] = xv[tid + 256 * i];
    __syncthreads();

    const int rg = tid >> 5;   // 0..7
    const int cg = tid & 31;   // 0..31

    float acc[8][16];
#pragma unroll
    for (int j2 = 0; j2 < 4; ++j2) {
        float4 bb = *(const float4*)&bias[j2 * 128 + cg * 4];
#pragma unroll
        for (int r = 0; r < 8; ++r) {
            acc[r][j2 * 4 + 0] = bb.x; acc[r][j2 * 4 + 1] = bb.y;
            acc[r][j2 * 4 + 2] = bb.z; acc[r][j2 * 4 + 3] = bb.w;
        }
    }

#pragma unroll 2
    for (int k = 0; k < 128; ++k) {
        float4 w0 = *(const float4*)&Wx[(size_t)k * G_ + 0 * 128 + cg * 4];
        float4 w1 = *(const float4*)&Wx[(size_t)k * G_ + 1 * 128 + cg * 4];
        float4 w2 = *(const float4*)&Wx[(size_t)k * G_ + 2 * 128 + cg * 4];
        float4 w3 = *(const float4*)&Wx[(size_t)k * G_ + 3 * 128 + cg * 4];
#pragma unroll
        for (int r = 0; r < 8; ++r) {
            float xval = xs[(rg * 8 + r) * 128 + k];
            acc[r][0]  = fmaf(xval, w0.x, acc[r][0]);
            acc[r][1]  = fmaf(xval, w0.y, acc[r][1]);
            acc[r][2]  = fmaf(xval, w0.z, acc[r][2]);
            acc[r][3]  = fmaf(xval, w0.w, acc[r][3]);
            acc[r][4]  = fmaf(xval, w1.x, acc[r][4]);
            acc[r][5]  = fmaf(xval, w1.y, acc[r][5]);
            acc[r][6]  = fmaf(xval, w1.z, acc[r][6]);
            acc[r][7]  = fmaf(xval, w1.w, acc[r][7]);
            acc[r][8]  = fmaf(xval, w2.x, acc[r][8]);
            acc[r][9]  = fmaf(xval, w2.y, acc[r][9]);
            acc[r][10] = fmaf(xval, w2.z, acc[r][10]);
            acc[r][11] = fmaf(xval, w2.w, acc[r][11]);
            acc[r][12] = fmaf(xval, w3.x, acc[r][12]);
            acc[r][13] = fmaf(xval, w3.y, acc[r][13]);
            acc[r][14] = fmaf(xval, w3.z, acc[r][14]);
            acc[r][15] = fmaf(xval, w3.w, acc[r][15]);
        }
    }

#pragma unroll
    for (int r = 0; r < 8; ++r) {
#pragma unroll
        for (int j2 = 0; j2 < 4; ++j2) {
            float4 v;
            v.x = acc[r][j2 * 4 + 0]; v.y = acc[r][j2 * 4 + 1];
            v.z = acc[r][j2 * 4 + 2]; v.w = acc[r][j2 * 4 + 3];
            *(float4*)&xg[((size_t)block_row + rg * 8 + r) * G_ + j2 * 128 + cg * 4] = v;
        }
    }
}

// ---------------- Kernel 2: recurrence via MFMA, 1 barrier/step ----------------
// Wave w, lane = q*16+cl: owns hidden unit hu = 16w+cl (q groups duplicate).
// Fragments whf[kk][gate]: B[k = kk*32+q*8+j][col = gate*128+hu].
// Per step: acc_gate init = xg[gate*128+hu]; 16 MFMA; 4 activations; c,h
// in-register; q==0 writes h bf16 to LDS buf p^1 + hs/cs to global;
// single raw s_barrier with lgkmcnt(0) only.

__global__ void __launch_bounds__(512)
__attribute__((amdgpu_waves_per_eu(2, 2)))
lstm_rnn_mfma(const float* __restrict__ xg, const float* __restrict__ Wh,
              float* __restrict__ hs, float* __restrict__ cs,
              float* __restrict__ hstate, float* __restrict__ cstate,
              int t0, int C) {
    const int b    = blockIdx.x;
    const int tid  = threadIdx.x;
    const int w    = tid >> 6;     // wave 0..7
    const int lane = tid & 63;
    const int q    = lane >> 4;    // k-quarter
    const int cl   = lane & 15;
    const int kb   = q * 8;
    const int hu   = w * 16 + cl;  // hidden unit owned

    __shared__ __align__(16) unsigned short h_u16[2][H_];

    // one-time: Wh B-fragments (16 frags = 64 VGPRs)
    v8bf whf[4][4];
#pragma unroll
    for (int kk = 0; kk < 4; ++kk) {
#pragma unroll
        for (int gc = 0; gc < 4; ++gc) {
            union { unsigned short s[8]; v8bf v; } uw;
#pragma unroll
            for (int j = 0; j < 8; ++j)
                uw.s[j] = f2bf(Wh[(size_t)(kk * 32 + kb + j) * G_ + gc * 128 + hu]);
            whf[kk][gc] = uw.v;
        }
    }

    float c = 0.0f;
    if (t0 > 0) c = cstate[b * H_ + hu];
    if (tid < H_) h_u16[0][tid] = f2bf((t0 > 0) ? hstate[b * H_ + tid] : 0.0f);
    __syncthreads();  // once per chunk; full drain acceptable here

    const float* xgb = xg + (size_t)b * C * G_;
    // 2-step-deep xg prefetch (per-gate scalars)
    float xA0 = xgb[hu],            xA1 = xgb[128 + hu];
    float xA2 = xgb[256 + hu],      xA3 = xgb[384 + hu];
    float xB0 = xgb[G_ + hu],       xB1 = xgb[G_ + 128 + hu];
    float xB2 = xgb[G_ + 256 + hu], xB3 = xgb[G_ + 384 + hu];

#define RNN_STEP(XV0, XV1, XV2, XV3, TCUR, TPF, PR, PW)                        \
    {                                                                          \
        f32x4 a0 = {XV0, XV0, XV0, XV0};                                       \
        f32x4 a1 = {XV1, XV1, XV1, XV1};                                       \
        f32x4 a2 = {XV2, XV2, XV2, XV2};                                       \
        f32x4 a3 = {XV3, XV3, XV3, XV3};                                       \
        int pf = ((TPF) < C) ? (TPF) : (C - 1);                                \
        const float* xp = xgb + (size_t)pf * G_;                               \
        XV0 = xp[hu];       XV1 = xp[128 + hu];                                \
        XV2 = xp[256 + hu]; XV3 = xp[384 + hu];                                \
        _Pragma("unroll")                                                      \
        for (int kk = 0; kk < 4; ++kk) {                                       \
            v8bf ha = *(const v8bf*)&h_u16[PR][kk * 32 + kb];                  \
            a0 = __builtin_amdgcn_mfma_f32_16x16x32_bf16(ha, whf[kk][0], a0, 0, 0, 0); \
            a1 = __builtin_amdgcn_mfma_f32_16x16x32_bf16(ha, whf[kk][1], a1, 0, 0, 0); \
            a2 = __builtin_amdgcn_mfma_f32_16x16x32_bf16(ha, whf[kk][2], a2, 0, 0, 0); \
            a3 = __builtin_amdgcn_mfma_f32_16x16x32_bf16(ha, whf[kk][3], a3, 0, 0, 0); \
        }                                                                      \
        float iv = sigmoid_(a0[0]);                                            \
        float fv = sigmoid_(a1[0]);                                            \
        float gv = tanh_(a2[0]);                                               \
        float ov = sigmoid_(a3[0]);                                            \
        c = fmaf(fv, c, iv * gv);                                              \
        float hnv = ov * tanh_(c);                                             \
        if (q == 0) {                                                          \
            h_u16[PW][hu] = f2bf(hnv);                                         \
            size_t off = ((size_t)b * T_ + (size_t)(t0 + (TCUR))) * H_ + hu;   \
            hs[off] = hnv; cs[off] = c;                                        \
        }                                                                      \
        asm volatile("s_waitcnt lgkmcnt(0)\n\ts_barrier" ::: "memory");        \
    }

    for (int t = 0; t < C; t += 2) {  // C is a multiple of 64 (even)
        RNN_STEP(xA0, xA1, xA2, xA3, t,     t + 2, 0, 1)
        RNN_STEP(xB0, xB1, xB2, xB3, t + 1, t + 3, 1, 0)
    }
#undef RNN_STEP

    if (q == 0) {
        // final h is in buf [C&1]==0 ... but simpler: recompute from register
        // state: last written hnv/c belong to this thread's hu.
        // h of final step was stored to h_u16[0][hu] (C even). Use registers:
        cstate[b * H_ + hu] = c;
    }
    // h final: read from LDS buf 0 (written by last step, barrier passed)
    if (tid < H_) {
        union { unsigned short s; } u; u.s = h_u16[0][tid];
        unsigned ui = ((unsigned)u.s) << 16;
        float hf; __builtin_memcpy(&hf, &ui, 4);
        hstate[b * H_ + tid] = hf;
    }
}

extern "C" void kernel_launch(void* const* d_in, const int* in_sizes, int n_in,
                              void* d_out, int out_size, void* d_ws, size_t ws_size,
                              hipStream_t stream) {
    const float* x    = (const float*)d_in[0];  // [64,2048,128]
    const float* Wx   = (const float*)d_in[1];  // [128,512]
    const float* Wh   = (const float*)d_in[2];  // [128,512]
    const float* bias = (const float*)d_in[3];  // [512]

    float* hs = (float*)d_out;                         // [64,2048,128]
    float* cs = hs + (size_t)B_ * T_ * H_;             // [64,2048,128]

    float* hstate = (float*)d_ws;                      // [64,128]
    float* cstate = hstate + B_ * H_;                  // [64,128]
    float* xg     = cstate + B_ * H_;                  // chunk scratch [B][C][512]

    const size_t state_floats = (size_t)2 * B_ * H_;
    size_t avail_bytes = (ws_size > state_floats * 4) ? (ws_size - state_floats * 4) : 0;
    const size_t bytes_per_t = (size_t)B_ * G_ * sizeof(float);

    int C = (int)(avail_bytes / bytes_per_t);
    if (C > T_) C = T_;
    C &= ~63;
    if (C < 64) C = 64;

    for (int t0 = 0; t0 < T_; t0 += C) {
        int Ci = (T_ - t0 < C) ? (T_ - t0) : C;
        dim3 ggrid((B_ * Ci) / 64);
        xg_gemm_kernel<<<ggrid, 256, 0, stream>>>(x, Wx, bias, xg, t0, Ci);
        lstm_rnn_mfma<<<B_, 512, 0, stream>>>(xg, Wh, hs, cs, hstate, cstate, t0, Ci);
    }
}

// Round 8
// 1277.356 us; speedup vs baseline: 1.7381x; 1.0701x over previous
//
#include <hip/hip_runtime.h>
#include <hip/hip_bf16.h>

// LSTM: B=64, T=2048, D=128, H=128, gates 4H=512.
// Kernel 1: xg = x@Wx + bias  (exact f32 GEMM, unchanged)
// Kernel 2: recurrence via bf16 MFMA, 64 blocks x 512 threads (8 waves).
//   R7 post-mortem: barrier/drain only ~85cyc/step; dominant stall is the
//   vmcnt wait on xg loads consumed at acc-INIT (pre-MFMA) with only ~1-2
//   intervals of prefetch depth vs ~900cyc HBM latency. This version:
//   - acc init = 0; xg added AFTER the MFMA block (wait moved ~200cyc later)
//   - 4-step-deep xg prefetch in 16 named registers (~2200cyc slack)
//   - unchanged: 1 lgkm-only barrier/step, h double-buffered in LDS,
//     64 VGPRs of Wh fragments resident @ waves_per_eu(2,2).

#define B_ 64
#define T_ 2048
#define D_ 128
#define H_ 128
#define G_ 512  // 4*H

typedef __bf16 v8bf __attribute__((ext_vector_type(8)));
typedef float f32x4 __attribute__((ext_vector_type(4)));

__device__ __forceinline__ float fast_exp2(float x) { return __builtin_amdgcn_exp2f(x); }
__device__ __forceinline__ float fast_rcp(float x)  { return __builtin_amdgcn_rcpf(x); }
__device__ __forceinline__ float sigmoid_(float x) {
    return fast_rcp(1.0f + fast_exp2(x * -1.44269504088896341f));
}
__device__ __forceinline__ float tanh_(float x) {
    // tanh(x) = 1 - 2/(1+2^(x*2*log2e)); saturates correctly at +-inf.
    return 1.0f - 2.0f * fast_rcp(1.0f + fast_exp2(x * 2.88539008177792682f));
}
__device__ __forceinline__ unsigned short f2bf(float f) {
    union { float f; unsigned u; } v; v.f = f;
    unsigned r = v.u + 0x7FFFu + ((v.u >> 16) & 1u);  // RNE
    return (unsigned short)(r >> 16);
}

// ---------------- Kernel 1: input projection GEMM (f32, exact) ----------------
__global__ void __launch_bounds__(256, 2)
xg_gemm_kernel(const float* __restrict__ x, const float* __restrict__ Wx,
               const float* __restrict__ bias, float* __restrict__ xg,
               int t0, int C) {
    __shared__ float xs[64 * 128];  // 32 KB: 64 rows of x
    const int tid = threadIdx.x;
    const int block_row = blockIdx.x * 64;   // row index in [0, B*C)
    const int b  = block_row / C;
    const int tl = block_row - b * C;

    const float* xrow = x + ((size_t)b * T_ + (size_t)(t0 + tl)) * D_;
    const float4* xv = (const float4*)xrow;
    float4* xsv = (float4*)xs;
#pragma unroll
    for (int i = 0; i < 8; ++i) xsv[tid + 256 * i] = xv[tid + 256 * i];
    __syncthreads();

    const int rg = tid >> 5;   // 0..7
    const int cg = tid & 31;   // 0..31

    float acc[8][16];
#pragma unroll
    for (int j2 = 0; j2 < 4; ++j2) {
        float4 bb = *(const float4*)&bias[j2 * 128 + cg * 4];
#pragma unroll
        for (int r = 0; r < 8; ++r) {
            acc[r][j2 * 4 + 0] = bb.x; acc[r][j2 * 4 + 1] = bb.y;
            acc[r][j2 * 4 + 2] = bb.z; acc[r][j2 * 4 + 3] = bb.w;
        }
    }

#pragma unroll 2
    for (int k = 0; k < 128; ++k) {
        float4 w0 = *(const float4*)&Wx[(size_t)k * G_ + 0 * 128 + cg * 4];
        float4 w1 = *(const float4*)&Wx[(size_t)k * G_ + 1 * 128 + cg * 4];
        float4 w2 = *(const float4*)&Wx[(size_t)k * G_ + 2 * 128 + cg * 4];
        float4 w3 = *(const float4*)&Wx[(size_t)k * G_ + 3 * 128 + cg * 4];
#pragma unroll
        for (int r = 0; r < 8; ++r) {
            float xval = xs[(rg * 8 + r) * 128 + k];
            acc[r][0]  = fmaf(xval, w0.x, acc[r][0]);
            acc[r][1]  = fmaf(xval, w0.y, acc[r][1]);
            acc[r][2]  = fmaf(xval, w0.z, acc[r][2]);
            acc[r][3]  = fmaf(xval, w0.w, acc[r][3]);
            acc[r][4]  = fmaf(xval, w1.x, acc[r][4]);
            acc[r][5]  = fmaf(xval, w1.y, acc[r][5]);
            acc[r][6]  = fmaf(xval, w1.z, acc[r][6]);
            acc[r][7]  = fmaf(xval, w1.w, acc[r][7]);
            acc[r][8]  = fmaf(xval, w2.x, acc[r][8]);
            acc[r][9]  = fmaf(xval, w2.y, acc[r][9]);
            acc[r][10] = fmaf(xval, w2.z, acc[r][10]);
            acc[r][11] = fmaf(xval, w2.w, acc[r][11]);
            acc[r][12] = fmaf(xval, w3.x, acc[r][12]);
            acc[r][13] = fmaf(xval, w3.y, acc[r][13]);
            acc[r][14] = fmaf(xval, w3.z, acc[r][14]);
            acc[r][15] = fmaf(xval, w3.w, acc[r][15]);
        }
    }

#pragma unroll
    for (int r = 0; r < 8; ++r) {
#pragma unroll
        for (int j2 = 0; j2 < 4; ++j2) {
            float4 v;
            v.x = acc[r][j2 * 4 + 0]; v.y = acc[r][j2 * 4 + 1];
            v.z = acc[r][j2 * 4 + 2]; v.w = acc[r][j2 * 4 + 3];
            *(float4*)&xg[((size_t)block_row + rg * 8 + r) * G_ + j2 * 128 + cg * 4] = v;
        }
    }
}

// ---------------- Kernel 2: recurrence via MFMA ----------------
// Wave w, lane = q*16+cl: owns hidden unit hu = 16w+cl (q groups duplicate).
// Per step: 16 MFMA (acc init 0); gate = acc[0] + xg (xg added POST-mfma,
// 4-step-deep prefetch); activations; c,h in-register; q==0 writes h bf16
// to LDS pingpong + hs/cs stores; single raw s_barrier + lgkmcnt(0).

__global__ void __launch_bounds__(512)
__attribute__((amdgpu_waves_per_eu(2, 2)))
lstm_rnn_mfma(const float* __restrict__ xg, const float* __restrict__ Wh,
              float* __restrict__ hs, float* __restrict__ cs,
              float* __restrict__ hstate, float* __restrict__ cstate,
              int t0, int C) {
    const int b    = blockIdx.x;
    const int tid  = threadIdx.x;
    const int w    = tid >> 6;     // wave 0..7
    const int lane = tid & 63;
    const int q    = lane >> 4;    // k-quarter
    const int cl   = lane & 15;
    const int kb   = q * 8;
    const int hu   = w * 16 + cl;  // hidden unit owned

    __shared__ __align__(16) unsigned short h_u16[2][H_];

    // one-time: Wh B-fragments (16 frags = 64 VGPRs)
    v8bf whf[4][4];
#pragma unroll
    for (int kk = 0; kk < 4; ++kk) {
#pragma unroll
        for (int gc = 0; gc < 4; ++gc) {
            union { unsigned short s[8]; v8bf v; } uw;
#pragma unroll
            for (int j = 0; j < 8; ++j)
                uw.s[j] = f2bf(Wh[(size_t)(kk * 32 + kb + j) * G_ + gc * 128 + hu]);
            whf[kk][gc] = uw.v;
        }
    }

    float c = 0.0f;
    if (t0 > 0) c = cstate[b * H_ + hu];
    if (tid < H_) h_u16[0][tid] = f2bf((t0 > 0) ? hstate[b * H_ + tid] : 0.0f);
    __syncthreads();  // once per chunk

    const float* xgb = xg + (size_t)b * C * G_;

    // 4-step-deep xg prefetch in named registers: xp{s}{gate}
#define LOADX(s, T_IDX) \
    float xp##s##0, xp##s##1, xp##s##2, xp##s##3; \
    { const float* xp_ = xgb + (size_t)(T_IDX) * G_; \
      xp##s##0 = xp_[hu];       xp##s##1 = xp_[128 + hu]; \
      xp##s##2 = xp_[256 + hu]; xp##s##3 = xp_[384 + hu]; }
    LOADX(0, 0) LOADX(1, 1) LOADX(2, 2) LOADX(3, 3)
#undef LOADX

#define RNN_STEP(PX0, PX1, PX2, PX3, TCUR, PR, PW)                             \
    {                                                                          \
        f32x4 a0 = {0.f, 0.f, 0.f, 0.f};                                       \
        f32x4 a1 = {0.f, 0.f, 0.f, 0.f};                                       \
        f32x4 a2 = {0.f, 0.f, 0.f, 0.f};                                       \
        f32x4 a3 = {0.f, 0.f, 0.f, 0.f};                                       \
        _Pragma("unroll")                                                      \
        for (int kk = 0; kk < 4; ++kk) {                                       \
            v8bf ha = *(const v8bf*)&h_u16[PR][kk * 32 + kb];                  \
            a0 = __builtin_amdgcn_mfma_f32_16x16x32_bf16(ha, whf[kk][0], a0, 0, 0, 0); \
            a1 = __builtin_amdgcn_mfma_f32_16x16x32_bf16(ha, whf[kk][1], a1, 0, 0, 0); \
            a2 = __builtin_amdgcn_mfma_f32_16x16x32_bf16(ha, whf[kk][2], a2, 0, 0, 0); \
            a3 = __builtin_amdgcn_mfma_f32_16x16x32_bf16(ha, whf[kk][3], a3, 0, 0, 0); \
        }                                                                      \
        /* xg added post-MFMA: vmcnt wait lands here, ~4 intervals deep */     \
        float iv = sigmoid_(a0[0] + PX0);                                      \
        float fv = sigmoid_(a1[0] + PX1);                                      \
        float gv = tanh_(a2[0] + PX2);                                         \
        float ov = sigmoid_(a3[0] + PX3);                                      \
        c = fmaf(fv, c, iv * gv);                                              \
        float hnv = ov * tanh_(c);                                             \
        /* reload this slot for step TCUR+4 */                                 \
        { int pf = ((TCUR) + 4 < C) ? ((TCUR) + 4) : (C - 1);                  \
          const float* xp_ = xgb + (size_t)pf * G_;                            \
          PX0 = xp_[hu];       PX1 = xp_[128 + hu];                            \
          PX2 = xp_[256 + hu]; PX3 = xp_[384 + hu]; }                          \
        if (q == 0) {                                                          \
            h_u16[PW][hu] = f2bf(hnv);                                         \
            size_t off = ((size_t)b * T_ + (size_t)(t0 + (TCUR))) * H_ + hu;   \
            hs[off] = hnv; cs[off] = c;                                        \
        }                                                                      \
        asm volatile("s_waitcnt lgkmcnt(0)\n\ts_barrier" ::: "memory");        \
    }

    for (int t = 0; t < C; t += 4) {  // C is a multiple of 64
        RNN_STEP(xp00, xp01, xp02, xp03, t,     0, 1)
        RNN_STEP(xp10, xp11, xp12, xp13, t + 1, 1, 0)
        RNN_STEP(xp20, xp21, xp22, xp23, t + 2, 0, 1)
        RNN_STEP(xp30, xp31, xp32, xp33, t + 3, 1, 0)
    }
#undef RNN_STEP

    if (q == 0) cstate[b * H_ + hu] = c;
    // final h in buf 0 (C multiple of 4; last step wrote PW=0)
    if (tid < H_) {
        unsigned ui = ((unsigned)h_u16[0][tid]) << 16;
        float hf; __builtin_memcpy(&hf, &ui, 4);
        hstate[b * H_ + tid] = hf;
    }
}

extern "C" void kernel_launch(void* const* d_in, const int* in_sizes, int n_in,
                              void* d_out, int out_size, void* d_ws, size_t ws_size,
                              hipStream_t stream) {
    const float* x    = (const float*)d_in[0];  // [64,2048,128]
    const float* Wx   = (const float*)d_in[1];  // [128,512]
    const float* Wh   = (const float*)d_in[2];  // [128,512]
    const float* bias = (const float*)d_in[3];  // [512]

    float* hs = (float*)d_out;                         // [64,2048,128]
    float* cs = hs + (size_t)B_ * T_ * H_;             // [64,2048,128]

    float* hstate = (float*)d_ws;                      // [64,128]
    float* cstate = hstate + B_ * H_;                  // [64,128]
    float* xg     = cstate + B_ * H_;                  // chunk scratch [B][C][512]

    const size_t state_floats = (size_t)2 * B_ * H_;
    size_t avail_bytes = (ws_size > state_floats * 4) ? (ws_size - state_floats * 4) : 0;
    const size_t bytes_per_t = (size_t)B_ * G_ * sizeof(float);

    int C = (int)(avail_bytes / bytes_per_t);
    if (C > T_) C = T_;
    C &= ~63;
    if (C < 64) C = 64;

    for (int t0 = 0; t0 < T_; t0 += C) {
        int Ci = (T_ - t0 < C) ? (T_ - t0) : C;
        dim3 ggrid((B_ * Ci) / 64);
        xg_gemm_kernel<<<ggrid, 256, 0, stream>>>(x, Wx, bias, xg, t0, Ci);
        lstm_rnn_mfma<<<B_, 512, 0, stream>>>(xg, Wh, hs, cs, hstate, cstate, t0, Ci);
    }
}